// Round 3
// baseline (1318.456 us; speedup 1.0000x reference)
//
#include <hip/hip_runtime.h>
#include <hip/hip_bf16.h>

#define N_NODES 50000
#define N_EDGES 800000
#define N_GRAPHS 64

typedef unsigned short u16;

#define NEGBIG -3.0e38f

__device__ __forceinline__ float bf2f(u16 u) {
    union { unsigned int i; float f; } v; v.i = ((unsigned int)u) << 16; return v.f;
}
__device__ __forceinline__ u16 f2bf(float f) {
    union { float f; unsigned int i; } v; v.f = f;
    unsigned int i = v.i;
    unsigned int r = i + 0x7fffu + ((i >> 16) & 1u);
    return (u16)(r >> 16);
}
__device__ __forceinline__ float asfloat(unsigned int u) {
    union { unsigned int i; float f; } v; v.i = u; return v.f;
}

// ---------------- CSR build (by dst) ----------------
__global__ __launch_bounds__(256) void k_hist(const int* __restrict__ dst, int* __restrict__ deg) {
    int e = blockIdx.x * 256 + threadIdx.x;
    if (e < N_EDGES) atomicAdd(&deg[dst[e]], 1);
}

// deg is turned into the scatter cursor in-place; rowptr gets the prefix sums.
__global__ __launch_bounds__(1024) void k_scan(int* __restrict__ deg, int* __restrict__ rowptr) {
    __shared__ int sums[1024];
    int t = threadIdx.x;
    const int CH = (N_NODES + 1023) / 1024; // 49
    int lo = t * CH;
    int hi = lo + CH; if (hi > N_NODES) hi = N_NODES;
    int s = 0;
    for (int i = lo; i < hi; i++) s += deg[i];
    sums[t] = s;
    __syncthreads();
    for (int off = 1; off < 1024; off <<= 1) {
        int v = (t >= off) ? sums[t - off] : 0;
        __syncthreads();
        sums[t] += v;
        __syncthreads();
    }
    int run = (t == 0) ? 0 : sums[t - 1];
    for (int i = lo; i < hi; i++) {
        int d = deg[i];
        rowptr[i] = run;
        deg[i] = run;      // becomes cursor
        run += d;
    }
    if (t == 1023) rowptr[N_NODES] = sums[1023];
}

__global__ __launch_bounds__(256) void k_scatter(const int* __restrict__ src, const int* __restrict__ dst,
                                                 const float* __restrict__ ew, int* __restrict__ cursor,
                                                 int* __restrict__ csr_src, float* __restrict__ csr_ew) {
    int e = blockIdx.x * 256 + threadIdx.x;
    if (e < N_EDGES) {
        int d = dst[e];
        int pos = atomicAdd(&cursor[d], 1);
        csr_src[pos] = src[e];
        csr_ew[pos] = ew[e];
    }
}

// ---------------- x = concat(nfeats,names)*centrality, fused gap0 gate logit ----------------
__global__ __launch_bounds__(256) void k_input(const float* __restrict__ nf, const float* __restrict__ nm,
                                               const float* __restrict__ cent, const float* __restrict__ Wg,
                                               const float* __restrict__ bg,
                                               u16* __restrict__ x, float* __restrict__ g) {
    int node = blockIdx.x * 4 + (threadIdx.x >> 6);
    int lane = threadIdx.x & 63;
    float v = (lane < 48) ? nf[(size_t)node * 48 + lane] : nm[(size_t)node * 16 + lane - 48];
    float xf = v * cent[node];
    x[(size_t)node * 64 + lane] = f2bf(xf);
    float p = xf * Wg[lane];
#pragma unroll
    for (int mm = 1; mm < 64; mm <<= 1) p += __shfl_xor(p, mm);
    if (lane == 0) g[node] = p + bg[0];
}

// ---------------- ft = X @ W (f32 vector GEMM, LDS-staged W), fused el/er ----------------
// ft stored as [N][64 d][4 h] bf16 (dim-major, head-minor) for the agg gather.
// thread t <-> output column t (head h = t>>6, dim d = t&63). 8 nodes per iter.
__global__ __launch_bounds__(256) void k_ftv(const float* __restrict__ W,
                                             const float* __restrict__ al, const float* __restrict__ ar,
                                             const u16* __restrict__ xin,
                                             u16* __restrict__ ft, float* __restrict__ el, float* __restrict__ er) {
    __shared__ float sW[64 * 256];   // natural layout [dd][col]
    __shared__ float xs[8][64];
    int t = threadIdx.x;
    int h = t >> 6, d = t & 63;
    for (int i = t; i < 64 * 256; i += 256) sW[i] = W[i];   // coalesced
    float alv = al[t], arv = ar[t];
    __syncthreads();

    for (int g = blockIdx.x; g < N_NODES / 8; g += gridDim.x) {
        __syncthreads();   // xs reuse fence
        for (int i = t; i < 512; i += 256) xs[i >> 6][i & 63] = bf2f(xin[(size_t)g * 512 + i]);
        __syncthreads();

        float acc[8] = {0.f, 0.f, 0.f, 0.f, 0.f, 0.f, 0.f, 0.f};
#pragma unroll
        for (int c4 = 0; c4 < 16; c4++) {
            // stride-1 across t -> conflict-free; 4 rows of W
            float w0 = sW[(c4 * 4 + 0) * 256 + t];
            float w1 = sW[(c4 * 4 + 1) * 256 + t];
            float w2 = sW[(c4 * 4 + 2) * 256 + t];
            float w3 = sW[(c4 * 4 + 3) * 256 + t];
#pragma unroll
            for (int j = 0; j < 8; j++) {
                float4 x4 = *(const float4*)(&xs[j][c4 * 4]);   // uniform broadcast
                acc[j] = fmaf(x4.w, w3, fmaf(x4.z, w2, fmaf(x4.y, w1, fmaf(x4.x, w0, acc[j]))));
            }
        }
#pragma unroll
        for (int j = 0; j < 8; j++) {
            int node = g * 8 + j;
            float v = acc[j];
            ft[(size_t)node * 256 + d * 4 + h] = f2bf(v);
            float pe = v * alv, pr = v * arv;
#pragma unroll
            for (int mm = 1; mm < 64; mm <<= 1) {
                pe += __shfl_xor(pe, mm);
                pr += __shfl_xor(pr, mm);
            }
            if (d == 0) { el[node * 4 + h] = pe; er[node * 4 + h] = pr; }
        }
    }
}

// ---------------- per-dst-node edge softmax + aggregation (wave per node) ----------------
__global__ __launch_bounds__(256) void k_agg(
    const u16* __restrict__ ft, const float4* __restrict__ el4, const float4* __restrict__ er4,
    const int* __restrict__ rowptr, const int* __restrict__ csr_src, const float* __restrict__ csr_ew,
    const float* __restrict__ bias, const float* __restrict__ Wg, const float* __restrict__ bg,
    u16* __restrict__ hout, float* __restrict__ gout) {
    int node = blockIdx.x * 4 + (threadIdx.x >> 6);
    int lane = threadIdx.x & 63;
    int beg = rowptr[node], end = rowptr[node + 1];
    float4 erv = er4[node];

    float m0 = NEGBIG, m1 = NEGBIG, m2 = NEGBIG, m3 = NEGBIG;
    float S0 = 0.f, S1 = 0.f, S2 = 0.f, S3 = 0.f;
    float a0 = 0.f, a1 = 0.f, a2 = 0.f, a3 = 0.f;

    for (int base = beg; base < end; base += 64) {
        int cnt = end - base; if (cnt > 64) cnt = 64;
        int sidx = 0; float w = 0.f;
        float e0 = NEGBIG, e1 = NEGBIG, e2 = NEGBIG, e3 = NEGBIG;
        if (lane < cnt) {
            sidx = csr_src[base + lane];
            w = csr_ew[base + lane];
            float4 elv = el4[sidx];
            float t0 = elv.x + erv.x, t1 = elv.y + erv.y, t2 = elv.z + erv.z, t3 = elv.w + erv.w;
            e0 = t0 > 0.f ? t0 : 0.2f * t0;
            e1 = t1 > 0.f ? t1 : 0.2f * t1;
            e2 = t2 > 0.f ? t2 : 0.2f * t2;
            e3 = t3 > 0.f ? t3 : 0.2f * t3;
        }
        float M0 = e0, M1 = e1, M2 = e2, M3 = e3;
#pragma unroll
        for (int mm = 1; mm < 64; mm <<= 1) {
            M0 = fmaxf(M0, __shfl_xor(M0, mm));
            M1 = fmaxf(M1, __shfl_xor(M1, mm));
            M2 = fmaxf(M2, __shfl_xor(M2, mm));
            M3 = fmaxf(M3, __shfl_xor(M3, mm));
        }
        float n0 = fmaxf(m0, M0), n1 = fmaxf(m1, M1), n2 = fmaxf(m2, M2), n3 = fmaxf(m3, M3);
        float al0 = __expf(m0 - n0), al1 = __expf(m1 - n1), al2 = __expf(m2 - n2), al3 = __expf(m3 - n3);
        S0 *= al0; S1 *= al1; S2 *= al2; S3 *= al3;
        a0 *= al0; a1 *= al1; a2 *= al2; a3 *= al3;
        m0 = n0; m1 = n1; m2 = n2; m3 = n3;
        float p0 = __expf(e0 - n0), p1 = __expf(e1 - n1), p2 = __expf(e2 - n2), p3 = __expf(e3 - n3);
        float s0 = p0, s1 = p1, s2 = p2, s3 = p3;
#pragma unroll
        for (int mm = 1; mm < 64; mm <<= 1) {
            s0 += __shfl_xor(s0, mm);
            s1 += __shfl_xor(s1, mm);
            s2 += __shfl_xor(s2, mm);
            s3 += __shfl_xor(s3, mm);
        }
        S0 += s0; S1 += s1; S2 += s2; S3 += s3;
        p0 *= w; p1 *= w; p2 *= w; p3 *= w;
        for (int k = 0; k < cnt; k++) {
            int sk = __shfl(sidx, k);
            float b0 = __shfl(p0, k), b1 = __shfl(p1, k), b2 = __shfl(p2, k), b3 = __shfl(p3, k);
            uint2 raw = *(const uint2*)(ft + (size_t)sk * 256 + lane * 4);
            a0 = fmaf(b0, asfloat(raw.x << 16), a0);
            a1 = fmaf(b1, asfloat(raw.x & 0xffff0000u), a1);
            a2 = fmaf(b2, asfloat(raw.y << 16), a2);
            a3 = fmaf(b3, asfloat(raw.y & 0xffff0000u), a3);
        }
    }
    float i0 = S0 > 0.f ? 1.f / S0 : 0.f;
    float i1 = S1 > 0.f ? 1.f / S1 : 0.f;
    float i2 = S2 > 0.f ? 1.f / S2 : 0.f;
    float i3 = S3 > 0.f ? 1.f / S3 : 0.f;
    float r0 = a0 * i0 + bias[lane];
    float r1 = a1 * i1 + bias[64 + lane];
    float r2 = a2 * i2 + bias[128 + lane];
    float r3 = a3 * i3 + bias[192 + lane];
    float o = (fmaxf(r0, 0.f) + fmaxf(r1, 0.f) + fmaxf(r2, 0.f) + fmaxf(r3, 0.f)) * 0.25f;
    hout[(size_t)node * 64 + lane] = f2bf(o);
    float pg = o * Wg[lane];
#pragma unroll
    for (int mm = 1; mm < 64; mm <<= 1) pg += __shfl_xor(pg, mm);
    if (lane == 0) gout[node] = pg + bg[0];
}

// ---------------- GlobalAttentionPooling: one block per graph (gid sorted) ----------------
__global__ __launch_bounds__(256) void k_gap(const u16* __restrict__ x, const float* __restrict__ g,
                                             const int* __restrict__ gid, float* __restrict__ hg) {
    int b = blockIdx.x;
    int t = threadIdx.x;
    int lo = 0, hi = N_NODES;
    while (lo < hi) { int mid = (lo + hi) >> 1; if (gid[mid] < b) lo = mid + 1; else hi = mid; }
    int s = lo;
    lo = 0; hi = N_NODES;
    while (lo < hi) { int mid = (lo + hi) >> 1; if (gid[mid] < b + 1) lo = mid + 1; else hi = mid; }
    int e = lo;

    __shared__ float red[256];
    float lm = NEGBIG;
    for (int i = s + t; i < e; i += 256) lm = fmaxf(lm, g[i]);
    red[t] = lm;
    __syncthreads();
    for (int off = 128; off > 0; off >>= 1) {
        if (t < off) red[t] = fmaxf(red[t], red[t + off]);
        __syncthreads();
    }
    float m = red[0];
    __syncthreads();

    int w = t >> 6, lane = t & 63;
    float acc = 0.f, Sp = 0.f;
    for (int i = s + w; i < e; i += 4) {
        float gate = __expf(g[i] - m);
        Sp += gate;
        acc += gate * bf2f(x[(size_t)i * 64 + lane]);
    }
    __shared__ float sacc[4][64];
    __shared__ float ssum[4];
    sacc[w][lane] = acc;
    if (lane == 0) ssum[w] = Sp;
    __syncthreads();
    if (t < 64) {
        float tot = sacc[0][t] + sacc[1][t] + sacc[2][t] + sacc[3][t];
        float S = ssum[0] + ssum[1] + ssum[2] + ssum[3];
        hg[b * 64 + t] = (S > 0.f) ? tot / S : 0.f;
    }
}

// ---------------- LSTM (4 steps) + final linear + sigmoid: one block per batch elem ----------------
__global__ __launch_bounds__(256) void k_lstm(const float* __restrict__ hg,
                                              const float* __restrict__ Wih, const float* __restrict__ Whh,
                                              const float* __restrict__ bih, const float* __restrict__ bhh,
                                              const float* __restrict__ Wc, const float* __restrict__ bc,
                                              float* __restrict__ out) {
    int b = blockIdx.x, t = threadIdx.x;
    __shared__ float h[64], c[64], G[256], xv[64], red[64];
    if (t < 64) { h[t] = 0.f; c[t] = 0.f; }
    __syncthreads();
    for (int step = 0; step < 4; step++) {
        if (t < 64) xv[t] = hg[step * 4096 + b * 64 + t];
        __syncthreads();
        float acc = bih[t] + bhh[t];
#pragma unroll 4
        for (int d = 0; d < 64; d++)
            acc += xv[d] * Wih[t * 64 + d] + h[d] * Whh[t * 64 + d];
        G[t] = acc;
        __syncthreads();
        if (t < 64) {
            float ig = 1.f / (1.f + __expf(-G[t]));
            float fg = 1.f / (1.f + __expf(-G[64 + t]));
            float gg = tanhf(G[128 + t]);
            float og = 1.f / (1.f + __expf(-G[192 + t]));
            float cn = fg * c[t] + ig * gg;
            c[t] = cn;
            h[t] = og * tanhf(cn);
        }
        __syncthreads();
    }
    if (t < 64) red[t] = h[t] * Wc[t];
    __syncthreads();
    if (t == 0) {
        float r = 0.f;
        for (int i = 0; i < 64; i++) r += red[i];
        r += bc[0];
        out[b] = 1.f / (1.f + __expf(-r));
    }
}

extern "C" void kernel_launch(void* const* d_in, const int* in_sizes, int n_in,
                              void* d_out, int out_size, void* d_ws, size_t ws_size,
                              hipStream_t stream) {
    const float* nf   = (const float*)d_in[0];
    const float* nm   = (const float*)d_in[1];
    const float* cent = (const float*)d_in[2];
    const float* ew   = (const float*)d_in[3];
    const int* src  = (const int*)d_in[4];
    const int* dst  = (const int*)d_in[5];
    const int* gid  = (const int*)d_in[6];
    const float* W[3]  = {(const float*)d_in[7],  (const float*)d_in[11], (const float*)d_in[15]};
    const float* al[3] = {(const float*)d_in[8],  (const float*)d_in[12], (const float*)d_in[16]};
    const float* ar[3] = {(const float*)d_in[9],  (const float*)d_in[13], (const float*)d_in[17]};
    const float* bb[3] = {(const float*)d_in[10], (const float*)d_in[14], (const float*)d_in[18]};
    const float* Wg[4] = {(const float*)d_in[19], (const float*)d_in[21], (const float*)d_in[23], (const float*)d_in[25]};
    const float* bg[4] = {(const float*)d_in[20], (const float*)d_in[22], (const float*)d_in[24], (const float*)d_in[26]};
    const float* Wih = (const float*)d_in[27];
    const float* Whh = (const float*)d_in[28];
    const float* bih = (const float*)d_in[29];
    const float* bhh = (const float*)d_in[30];
    const float* Wc  = (const float*)d_in[31];
    const float* bc  = (const float*)d_in[32];
    float* out = (float*)d_out;

    char* p = (char*)d_ws;
    size_t off = 0;
    auto A = [&](size_t bytes) -> char* {
        char* r = p + off;
        off += (bytes + 255) & ~(size_t)255;
        return r;
    };
    // ~40.6 MB total
    u16*   ftb     = (u16*)  A((size_t)N_NODES * 256 * 2);   // 25.6 MB
    u16*   nodebuf = (u16*)  A((size_t)N_NODES * 64 * 2);    // 6.4 MB (x/h, in-place across layers)
    int*   csr_src = (int*)  A((size_t)N_EDGES * 4);         // 3.2 MB
    float* csr_ew  = (float*)A((size_t)N_EDGES * 4);         // 3.2 MB
    float* el      = (float*)A((size_t)N_NODES * 4 * 4);     // 0.8 MB
    float* er      = (float*)A((size_t)N_NODES * 4 * 4);     // 0.8 MB
    float* gbuf    = (float*)A((size_t)N_NODES * 4);         // 0.2 MB
    int*   rowptr  = (int*)  A((size_t)(N_NODES + 1) * 4);
    int*   deg     = (int*)  A((size_t)(N_NODES + 1) * 4);   // doubles as scatter cursor
    float* hg      = (float*)A((size_t)4 * 64 * 64 * 4);

    hipMemsetAsync(deg, 0, (N_NODES + 1) * sizeof(int), stream);
    k_hist<<<(N_EDGES + 255) / 256, 256, 0, stream>>>(dst, deg);
    k_scan<<<1, 1024, 0, stream>>>(deg, rowptr);
    k_scatter<<<(N_EDGES + 255) / 256, 256, 0, stream>>>(src, dst, ew, deg, csr_src, csr_ew);

    k_input<<<N_NODES / 4, 256, 0, stream>>>(nf, nm, cent, Wg[0], bg[0], nodebuf, gbuf);
    k_gap<<<N_GRAPHS, 256, 0, stream>>>(nodebuf, gbuf, gid, hg);

    for (int l = 0; l < 3; l++) {
        k_ftv<<<1024, 256, 0, stream>>>(W[l], al[l], ar[l], nodebuf, ftb, el, er);
        k_agg<<<N_NODES / 4, 256, 0, stream>>>(ftb, (const float4*)el, (const float4*)er, rowptr,
                                               csr_src, csr_ew, bb[l], Wg[l + 1], bg[l + 1], nodebuf, gbuf);
        k_gap<<<N_GRAPHS, 256, 0, stream>>>(nodebuf, gbuf, gid, hg + (size_t)(l + 1) * 4096);
    }
    k_lstm<<<N_GRAPHS, 256, 0, stream>>>(hg, Wih, Whh, bih, bhh, Wc, bc, out);
}

// Round 4
// 927.474 us; speedup vs baseline: 1.4216x; 1.4216x over previous
//
#include <hip/hip_runtime.h>
#include <hip/hip_bf16.h>

#define N_NODES 50000
#define N_EDGES 800000
#define N_GRAPHS 64

typedef unsigned short u16;
typedef short s16x8 __attribute__((ext_vector_type(8)));
typedef float f32x4 __attribute__((ext_vector_type(4)));

#define NEGBIG -3.0e38f

__device__ __forceinline__ float bf2f(u16 u) {
    union { unsigned int i; float f; } v; v.i = ((unsigned int)u) << 16; return v.f;
}
__device__ __forceinline__ u16 f2bf(float f) {
    union { float f; unsigned int i; } v; v.f = f;
    unsigned int i = v.i;
    unsigned int r = i + 0x7fffu + ((i >> 16) & 1u);
    return (u16)(r >> 16);
}
__device__ __forceinline__ float asfloat(unsigned int u) {
    union { unsigned int i; float f; } v; v.i = u; return v.f;
}

// ---------------- CSR build (by dst) ----------------
__global__ __launch_bounds__(256) void k_hist(const int* __restrict__ dst, int* __restrict__ deg) {
    int e = blockIdx.x * 256 + threadIdx.x;
    if (e < N_EDGES) atomicAdd(&deg[dst[e]], 1);
}

// deg is turned into the scatter cursor in-place; rowptr gets the prefix sums.
__global__ __launch_bounds__(1024) void k_scan(int* __restrict__ deg, int* __restrict__ rowptr) {
    __shared__ int sums[1024];
    int t = threadIdx.x;
    const int CH = (N_NODES + 1023) / 1024; // 49
    int lo = t * CH;
    int hi = lo + CH; if (hi > N_NODES) hi = N_NODES;
    int s = 0;
    for (int i = lo; i < hi; i++) s += deg[i];
    sums[t] = s;
    __syncthreads();
    for (int off = 1; off < 1024; off <<= 1) {
        int v = (t >= off) ? sums[t - off] : 0;
        __syncthreads();
        sums[t] += v;
        __syncthreads();
    }
    int run = (t == 0) ? 0 : sums[t - 1];
    for (int i = lo; i < hi; i++) {
        int d = deg[i];
        rowptr[i] = run;
        deg[i] = run;      // becomes cursor
        run += d;
    }
    if (t == 1023) rowptr[N_NODES] = sums[1023];
}

__global__ __launch_bounds__(256) void k_scatter(const int* __restrict__ src, const int* __restrict__ dst,
                                                 const float* __restrict__ ew, int* __restrict__ cursor,
                                                 int* __restrict__ csr_src, float* __restrict__ csr_ew) {
    int e = blockIdx.x * 256 + threadIdx.x;
    if (e < N_EDGES) {
        int d = dst[e];
        int pos = atomicAdd(&cursor[d], 1);
        csr_src[pos] = src[e];
        csr_ew[pos] = ew[e];
    }
}

// ---------------- W (f32, [64][256]) -> Wt (bf16, [256 col][64 d]) ----------------
__global__ __launch_bounds__(256) void k_prep(const float* __restrict__ W1, const float* __restrict__ W2,
                                              const float* __restrict__ W3, u16* __restrict__ Wt) {
    const float* W = (blockIdx.x == 0) ? W1 : (blockIdx.x == 1) ? W2 : W3;
    u16* o = Wt + (size_t)blockIdx.x * 64 * 256;
    for (int i = threadIdx.x; i < 64 * 256; i += 256) {
        int col = i >> 6, d = i & 63;
        o[i] = f2bf(W[d * 256 + col]);   // write coalesced, read strided (L2)
    }
}

// ---------------- x = concat(nfeats,names)*centrality, fused gap0 gate logit ----------------
__global__ __launch_bounds__(256) void k_input(const float* __restrict__ nf, const float* __restrict__ nm,
                                               const float* __restrict__ cent, const float* __restrict__ Wg,
                                               const float* __restrict__ bg,
                                               u16* __restrict__ x, float* __restrict__ g) {
    int node = blockIdx.x * 4 + (threadIdx.x >> 6);
    int lane = threadIdx.x & 63;
    float v = (lane < 48) ? nf[(size_t)node * 48 + lane] : nm[(size_t)node * 16 + lane - 48];
    float xf = v * cent[node];
    x[(size_t)node * 64 + lane] = f2bf(xf);
    float p = xf * Wg[lane];
#pragma unroll
    for (int mm = 1; mm < 64; mm <<= 1) p += __shfl_xor(p, mm);
    if (lane == 0) g[node] = p + bg[0];
}

// ---------------- ft = X @ W via MFMA 16x16x32 bf16, epilogue computes el/er ----------------
// ft stored as [N][64 d][4 h] bf16 (dim-major, head-minor) for the agg gather.
// wave w = head; 16 nodes per block.
__global__ __launch_bounds__(256) void k_ft(const u16* __restrict__ X, const u16* __restrict__ Wt,
                                            const float* __restrict__ al, const float* __restrict__ ar,
                                            u16* __restrict__ ft, float* __restrict__ el, float* __restrict__ er) {
    int w = threadIdx.x >> 6;      // wave = head (cols w*64..w*64+63)
    int lane = threadIdx.x & 63;
    int quad = lane >> 4, c = lane & 15;
    int n0 = blockIdx.x * 16;

    f32x4 acc[4];
#pragma unroll
    for (int t = 0; t < 4; t++) acc[t] = (f32x4){0.f, 0.f, 0.f, 0.f};

#pragma unroll
    for (int kh = 0; kh < 2; kh++) {
        // A[m=lane&15][k=quad*8+j] : node n0+c, k offset kh*32+quad*8
        s16x8 a = *(const s16x8*)(X + (size_t)(n0 + c) * 64 + kh * 32 + quad * 8);
#pragma unroll
        for (int t = 0; t < 4; t++) {
            int col = w * 64 + t * 16 + c;   // B[k=quad*8+j][n=lane&15] from Wt[col][k]
            s16x8 b = *(const s16x8*)(Wt + (size_t)col * 64 + kh * 32 + quad * 8);
            acc[t] = __builtin_amdgcn_mfma_f32_16x16x32_bf16(a, b, acc[t], 0, 0, 0);
        }
    }

    float alv[4], arv[4];
#pragma unroll
    for (int t = 0; t < 4; t++) {
        alv[t] = al[w * 64 + t * 16 + c];
        arv[t] = ar[w * 64 + t * 16 + c];
    }
    float pel[4] = {0.f, 0.f, 0.f, 0.f}, per[4] = {0.f, 0.f, 0.f, 0.f};
    // C/D layout: col = lane&15, row = quad*4 + reg   [measured m89]
#pragma unroll
    for (int t = 0; t < 4; t++) {
#pragma unroll
        for (int r = 0; r < 4; r++) {
            float v = acc[t][r];
            int node = n0 + quad * 4 + r;
            int d = t * 16 + c;
            ft[(size_t)node * 256 + d * 4 + w] = f2bf(v);
            pel[r] += v * alv[t];
            per[r] += v * arv[t];
        }
    }
    // reduce over the 16 lanes (c) of each quad
#pragma unroll
    for (int r = 0; r < 4; r++) {
#pragma unroll
        for (int mm = 1; mm < 16; mm <<= 1) {
            pel[r] += __shfl_xor(pel[r], mm);
            per[r] += __shfl_xor(per[r], mm);
        }
    }
    if (c == 0) {
#pragma unroll
        for (int r = 0; r < 4; r++) {
            int node = n0 + quad * 4 + r;
            el[node * 4 + w] = pel[r];
            er[node * 4 + w] = per[r];
        }
    }
}

// ---------------- per-dst-node edge softmax + aggregation (wave per node) ----------------
__global__ __launch_bounds__(256) void k_agg(
    const u16* __restrict__ ft, const float4* __restrict__ el4, const float4* __restrict__ er4,
    const int* __restrict__ rowptr, const int* __restrict__ csr_src, const float* __restrict__ csr_ew,
    const float* __restrict__ bias, const float* __restrict__ Wg, const float* __restrict__ bg,
    u16* __restrict__ hout, float* __restrict__ gout) {
    int node = blockIdx.x * 4 + (threadIdx.x >> 6);
    int lane = threadIdx.x & 63;
    int beg = rowptr[node], end = rowptr[node + 1];
    float4 erv = er4[node];

    float m0 = NEGBIG, m1 = NEGBIG, m2 = NEGBIG, m3 = NEGBIG;
    float S0 = 0.f, S1 = 0.f, S2 = 0.f, S3 = 0.f;
    float a0 = 0.f, a1 = 0.f, a2 = 0.f, a3 = 0.f;

    for (int base = beg; base < end; base += 64) {
        int cnt = end - base; if (cnt > 64) cnt = 64;
        int sidx = 0; float w = 0.f;
        float e0 = NEGBIG, e1 = NEGBIG, e2 = NEGBIG, e3 = NEGBIG;
        if (lane < cnt) {
            sidx = csr_src[base + lane];
            w = csr_ew[base + lane];
            float4 elv = el4[sidx];
            float t0 = elv.x + erv.x, t1 = elv.y + erv.y, t2 = elv.z + erv.z, t3 = elv.w + erv.w;
            e0 = t0 > 0.f ? t0 : 0.2f * t0;
            e1 = t1 > 0.f ? t1 : 0.2f * t1;
            e2 = t2 > 0.f ? t2 : 0.2f * t2;
            e3 = t3 > 0.f ? t3 : 0.2f * t3;
        }
        float M0 = e0, M1 = e1, M2 = e2, M3 = e3;
#pragma unroll
        for (int mm = 1; mm < 64; mm <<= 1) {
            M0 = fmaxf(M0, __shfl_xor(M0, mm));
            M1 = fmaxf(M1, __shfl_xor(M1, mm));
            M2 = fmaxf(M2, __shfl_xor(M2, mm));
            M3 = fmaxf(M3, __shfl_xor(M3, mm));
        }
        float n0 = fmaxf(m0, M0), n1 = fmaxf(m1, M1), n2 = fmaxf(m2, M2), n3 = fmaxf(m3, M3);
        float al0 = __expf(m0 - n0), al1 = __expf(m1 - n1), al2 = __expf(m2 - n2), al3 = __expf(m3 - n3);
        S0 *= al0; S1 *= al1; S2 *= al2; S3 *= al3;
        a0 *= al0; a1 *= al1; a2 *= al2; a3 *= al3;
        m0 = n0; m1 = n1; m2 = n2; m3 = n3;
        float p0 = __expf(e0 - n0), p1 = __expf(e1 - n1), p2 = __expf(e2 - n2), p3 = __expf(e3 - n3);
        float s0 = p0, s1 = p1, s2 = p2, s3 = p3;
#pragma unroll
        for (int mm = 1; mm < 64; mm <<= 1) {
            s0 += __shfl_xor(s0, mm);
            s1 += __shfl_xor(s1, mm);
            s2 += __shfl_xor(s2, mm);
            s3 += __shfl_xor(s3, mm);
        }
        S0 += s0; S1 += s1; S2 += s2; S3 += s3;
        p0 *= w; p1 *= w; p2 *= w; p3 *= w;
        for (int k = 0; k < cnt; k++) {
            int sk = __shfl(sidx, k);
            float b0 = __shfl(p0, k), b1 = __shfl(p1, k), b2 = __shfl(p2, k), b3 = __shfl(p3, k);
            uint2 raw = *(const uint2*)(ft + (size_t)sk * 256 + lane * 4);
            a0 = fmaf(b0, asfloat(raw.x << 16), a0);
            a1 = fmaf(b1, asfloat(raw.x & 0xffff0000u), a1);
            a2 = fmaf(b2, asfloat(raw.y << 16), a2);
            a3 = fmaf(b3, asfloat(raw.y & 0xffff0000u), a3);
        }
    }
    float i0 = S0 > 0.f ? 1.f / S0 : 0.f;
    float i1 = S1 > 0.f ? 1.f / S1 : 0.f;
    float i2 = S2 > 0.f ? 1.f / S2 : 0.f;
    float i3 = S3 > 0.f ? 1.f / S3 : 0.f;
    float r0 = a0 * i0 + bias[lane];
    float r1 = a1 * i1 + bias[64 + lane];
    float r2 = a2 * i2 + bias[128 + lane];
    float r3 = a3 * i3 + bias[192 + lane];
    float o = (fmaxf(r0, 0.f) + fmaxf(r1, 0.f) + fmaxf(r2, 0.f) + fmaxf(r3, 0.f)) * 0.25f;
    hout[(size_t)node * 64 + lane] = f2bf(o);
    float pg = o * Wg[lane];
#pragma unroll
    for (int mm = 1; mm < 64; mm <<= 1) pg += __shfl_xor(pg, mm);
    if (lane == 0) gout[node] = pg + bg[0];
}

// ---------------- GlobalAttentionPooling: one block per graph (gid sorted) ----------------
__global__ __launch_bounds__(256) void k_gap(const u16* __restrict__ x, const float* __restrict__ g,
                                             const int* __restrict__ gid, float* __restrict__ hg) {
    int b = blockIdx.x;
    int t = threadIdx.x;
    int lo = 0, hi = N_NODES;
    while (lo < hi) { int mid = (lo + hi) >> 1; if (gid[mid] < b) lo = mid + 1; else hi = mid; }
    int s = lo;
    lo = 0; hi = N_NODES;
    while (lo < hi) { int mid = (lo + hi) >> 1; if (gid[mid] < b + 1) lo = mid + 1; else hi = mid; }
    int e = lo;

    __shared__ float red[256];
    float lm = NEGBIG;
    for (int i = s + t; i < e; i += 256) lm = fmaxf(lm, g[i]);
    red[t] = lm;
    __syncthreads();
    for (int off = 128; off > 0; off >>= 1) {
        if (t < off) red[t] = fmaxf(red[t], red[t + off]);
        __syncthreads();
    }
    float m = red[0];
    __syncthreads();

    int w = t >> 6, lane = t & 63;
    float acc = 0.f, Sp = 0.f;
    for (int i = s + w; i < e; i += 4) {
        float gate = __expf(g[i] - m);
        Sp += gate;
        acc += gate * bf2f(x[(size_t)i * 64 + lane]);
    }
    __shared__ float sacc[4][64];
    __shared__ float ssum[4];
    sacc[w][lane] = acc;
    if (lane == 0) ssum[w] = Sp;
    __syncthreads();
    if (t < 64) {
        float tot = sacc[0][t] + sacc[1][t] + sacc[2][t] + sacc[3][t];
        float S = ssum[0] + ssum[1] + ssum[2] + ssum[3];
        hg[b * 64 + t] = (S > 0.f) ? tot / S : 0.f;
    }
}

// ---------------- LSTM (4 steps) + final linear + sigmoid: one block per batch elem ----------------
__global__ __launch_bounds__(256) void k_lstm(const float* __restrict__ hg,
                                              const float* __restrict__ Wih, const float* __restrict__ Whh,
                                              const float* __restrict__ bih, const float* __restrict__ bhh,
                                              const float* __restrict__ Wc, const float* __restrict__ bc,
                                              float* __restrict__ out) {
    int b = blockIdx.x, t = threadIdx.x;
    __shared__ float h[64], c[64], G[256], xv[64], red[64];
    if (t < 64) { h[t] = 0.f; c[t] = 0.f; }
    __syncthreads();
    for (int step = 0; step < 4; step++) {
        if (t < 64) xv[t] = hg[step * 4096 + b * 64 + t];
        __syncthreads();
        float acc = bih[t] + bhh[t];
#pragma unroll 4
        for (int d = 0; d < 64; d++)
            acc += xv[d] * Wih[t * 64 + d] + h[d] * Whh[t * 64 + d];
        G[t] = acc;
        __syncthreads();
        if (t < 64) {
            float ig = 1.f / (1.f + __expf(-G[t]));
            float fg = 1.f / (1.f + __expf(-G[64 + t]));
            float gg = tanhf(G[128 + t]);
            float og = 1.f / (1.f + __expf(-G[192 + t]));
            float cn = fg * c[t] + ig * gg;
            c[t] = cn;
            h[t] = og * tanhf(cn);
        }
        __syncthreads();
    }
    if (t < 64) red[t] = h[t] * Wc[t];
    __syncthreads();
    if (t == 0) {
        float r = 0.f;
        for (int i = 0; i < 64; i++) r += red[i];
        r += bc[0];
        out[b] = 1.f / (1.f + __expf(-r));
    }
}

extern "C" void kernel_launch(void* const* d_in, const int* in_sizes, int n_in,
                              void* d_out, int out_size, void* d_ws, size_t ws_size,
                              hipStream_t stream) {
    const float* nf   = (const float*)d_in[0];
    const float* nm   = (const float*)d_in[1];
    const float* cent = (const float*)d_in[2];
    const float* ew   = (const float*)d_in[3];
    const int* src  = (const int*)d_in[4];
    const int* dst  = (const int*)d_in[5];
    const int* gid  = (const int*)d_in[6];
    const float* W[3]  = {(const float*)d_in[7],  (const float*)d_in[11], (const float*)d_in[15]};
    const float* al[3] = {(const float*)d_in[8],  (const float*)d_in[12], (const float*)d_in[16]};
    const float* ar[3] = {(const float*)d_in[9],  (const float*)d_in[13], (const float*)d_in[17]};
    const float* bb[3] = {(const float*)d_in[10], (const float*)d_in[14], (const float*)d_in[18]};
    const float* Wg[4] = {(const float*)d_in[19], (const float*)d_in[21], (const float*)d_in[23], (const float*)d_in[25]};
    const float* bg[4] = {(const float*)d_in[20], (const float*)d_in[22], (const float*)d_in[24], (const float*)d_in[26]};
    const float* Wih = (const float*)d_in[27];
    const float* Whh = (const float*)d_in[28];
    const float* bih = (const float*)d_in[29];
    const float* bhh = (const float*)d_in[30];
    const float* Wc  = (const float*)d_in[31];
    const float* bc  = (const float*)d_in[32];
    float* out = (float*)d_out;

    char* p = (char*)d_ws;
    size_t off = 0;
    auto A = [&](size_t bytes) -> char* {
        char* r = p + off;
        off += (bytes + 255) & ~(size_t)255;
        return r;
    };
    // ~41 MB total
    u16*   ftb     = (u16*)  A((size_t)N_NODES * 256 * 2);   // 25.6 MB
    u16*   nodebuf = (u16*)  A((size_t)N_NODES * 64 * 2);    // 6.4 MB (x/h, in-place across layers)
    int*   csr_src = (int*)  A((size_t)N_EDGES * 4);         // 3.2 MB
    float* csr_ew  = (float*)A((size_t)N_EDGES * 4);         // 3.2 MB
    float* el      = (float*)A((size_t)N_NODES * 4 * 4);     // 0.8 MB
    float* er      = (float*)A((size_t)N_NODES * 4 * 4);     // 0.8 MB
    float* gbuf    = (float*)A((size_t)N_NODES * 4);         // 0.2 MB
    int*   rowptr  = (int*)  A((size_t)(N_NODES + 1) * 4);
    int*   deg     = (int*)  A((size_t)(N_NODES + 1) * 4);   // doubles as scatter cursor
    float* hg      = (float*)A((size_t)4 * 64 * 64 * 4);
    u16*   Wt      = (u16*)  A((size_t)3 * 64 * 256 * 2);    // bf16 W^T for MFMA B-frags

    hipMemsetAsync(deg, 0, (N_NODES + 1) * sizeof(int), stream);
    k_hist<<<(N_EDGES + 255) / 256, 256, 0, stream>>>(dst, deg);
    k_scan<<<1, 1024, 0, stream>>>(deg, rowptr);
    k_scatter<<<(N_EDGES + 255) / 256, 256, 0, stream>>>(src, dst, ew, deg, csr_src, csr_ew);
    k_prep<<<3, 256, 0, stream>>>(W[0], W[1], W[2], Wt);

    k_input<<<N_NODES / 4, 256, 0, stream>>>(nf, nm, cent, Wg[0], bg[0], nodebuf, gbuf);
    k_gap<<<N_GRAPHS, 256, 0, stream>>>(nodebuf, gbuf, gid, hg);

    for (int l = 0; l < 3; l++) {
        k_ft<<<N_NODES / 16, 256, 0, stream>>>(nodebuf, Wt + (size_t)l * 64 * 256, al[l], ar[l], ftb, el, er);
        k_agg<<<N_NODES / 4, 256, 0, stream>>>(ftb, (const float4*)el, (const float4*)er, rowptr,
                                               csr_src, csr_ew, bb[l], Wg[l + 1], bg[l + 1], nodebuf, gbuf);
        k_gap<<<N_GRAPHS, 256, 0, stream>>>(nodebuf, gbuf, gid, hg + (size_t)(l + 1) * 4096);
    }
    k_lstm<<<N_GRAPHS, 256, 0, stream>>>(hg, Wih, Whh, bih, bhh, Wc, bc, out);
}